// Round 7
// baseline (327.820 us; speedup 1.0000x reference)
//
#include <hip/hip_runtime.h>
#include <hip/hip_bf16.h>
#include <hip/hip_cooperative_groups.h>

namespace cg = cooperative_groups;

#define GAT_ALPHA 0.2f
#define LOG2E 1.4426950408889634f

typedef float f32x4 __attribute__((ext_vector_type(4)));
typedef int   i32x4 __attribute__((ext_vector_type(4)));
typedef short bf16x8 __attribute__((ext_vector_type(8)));

static constexpr int Nn  = 2048;
static constexpr int FIN = 256;
static constexpr int FO  = 128;

static __device__ __forceinline__ unsigned short f2bf(float x) {
    __hip_bfloat16 h = __float2bfloat16(x);
    return __builtin_bit_cast(unsigned short, h);
}
static __device__ __forceinline__ float bf2f(unsigned short u) {
    unsigned int v = ((unsigned int)u) << 16;
    return __builtin_bit_cast(float, v);
}

// ===========================================================================
// FUSED single cooperative kernel. 512 blocks = 8 batches x 64 i-tiles(32).
// Phase 0 (per block, all independent):
//   a) pack own 32 adj rows -> LDS bitmask  (the only mandatory HBM stream)
//   b) stage W -> WT bf16 LDS (per-block)   c) wa = W@a inline (k = thread)
//   d) fp32-exact scores for own 32 rows + per-batch max via atomicMax
//   e) MFMA Wh for own 32 rows -> 8 KB contiguous pre-swizzled WhB slice
// grid.sync()
// Phase 1: proven r6 barrier-free K-loop (masks in LDS from phase 0a;
//   B-frags contiguous 1 KB wave loads from WhB). sdl/accbuf alias WT.
// LDS: 67584 (WT | sdl+accbuf) + 8704 msk + 2048 wal + 2048 sred + 128 + 128
//    = 80640 B -> exactly 2 blocks/CU -> all 512 blocks co-resident.
// ===========================================================================
__global__ __launch_bounds__(256, 2) void gat_fused(
        const float* __restrict__ h, const int* __restrict__ adj,
        const float* __restrict__ W, const float* __restrict__ a,
        unsigned short* __restrict__ WhB, float* __restrict__ s_src,
        float* __restrict__ s_dst, unsigned int* __restrict__ md_key,
        float* __restrict__ out)
{
    __shared__ __align__(16) unsigned short WTbuf[128 * 264];  // 67584 B
    __shared__ unsigned long long msk[32][34];                 // 8704 B
    __shared__ float wal[512];
    __shared__ float sred[32][8][2];
    __shared__ float red32[32];
    __shared__ float l_red[32];

    const int t = threadIdx.x, w = t >> 6, lane = t & 63;
    const int n16 = lane & 15, quad = lane >> 4;
    const int b  = blockIdx.x & 7;
    const int i0 = (blockIdx.x >> 3) << 5;

    unsigned short (*WT)[264] = (unsigned short (*)[264])WTbuf;
    float* sdl = (float*)WTbuf;                 // phase 1: [2048]
    float (*acb)[132] = (float (*)[132])((float*)WTbuf + 2048);  // phase 1: [64][132]

    // ---- 0a: adj -> bitmask (proven r6 prologue) ----
    {
        const int* ab = adj + ((size_t)(b * Nn + i0)) * Nn;
        unsigned int* mskw = (unsigned int*)&msk[0][0];
        #pragma unroll 2
        for (int s = 0; s < 8; ++s) {
            const int* p = ab + (s << 13) + (t << 5);
            unsigned int m = 0;
            #pragma unroll
            for (int c = 0; c < 8; ++c) {
                i32x4 v = *(const i32x4*)(p + (c << 2));
                m |= (v[0] > 0 ? 1u : 0u) << (c * 4 + 0);
                m |= (v[1] > 0 ? 1u : 0u) << (c * 4 + 1);
                m |= (v[2] > 0 ? 1u : 0u) << (c * 4 + 2);
                m |= (v[3] > 0 ? 1u : 0u) << (c * 4 + 3);
            }
            const int wi = (s << 8) + t;
            mskw[(wi >> 6) * 68 + (wi & 63)] = m;
        }
    }
    // ---- 0b: W -> WT bf16 ----
    #pragma unroll
    for (int c = 0; c < 32; ++c) {
        int flat = c * 1024 + t * 4;
        int k = flat >> 7, f = flat & 127;
        f32x4 wv = *(const f32x4*)&W[flat];
        WT[f + 0][k] = f2bf(wv[0]);
        WT[f + 1][k] = f2bf(wv[1]);
        WT[f + 2][k] = f2bf(wv[2]);
        WT[f + 3][k] = f2bf(wv[3]);
    }
    // ---- 0c: wa inline, thread t handles k = t ----
    {
        const float* wr = W + (size_t)t * FO;
        float ps = 0.f, pv = 0.f;
        #pragma unroll
        for (int f = 0; f < FO; f += 4) {
            f32x4 wv = *(const f32x4*)(wr + f);
            f32x4 as = *(const f32x4*)(a + f);
            f32x4 ad = *(const f32x4*)(a + FO + f);
            ps += wv[0]*as[0] + wv[1]*as[1] + wv[2]*as[2] + wv[3]*as[3];
            pv += wv[0]*ad[0] + wv[1]*ad[1] + wv[2]*ad[2] + wv[3]*ad[3];
        }
        wal[t] = ps; wal[256 + t] = pv;
    }
    __syncthreads();
    // ---- 0d: fp32-exact scores, 8 threads/row x 32 k ----
    {
        const int r = t >> 3, seg = t & 7;
        const float* hp  = h + ((size_t)(b * Nn + i0 + r)) * FIN + seg * 32;
        const float* was = &wal[seg * 32];
        const float* wad = &wal[256 + seg * 32];
        float ps = 0.f, pv = 0.f;
        #pragma unroll
        for (int j = 0; j < 32; j += 4) {
            f32x4 hv = *(const f32x4*)(hp + j);
            f32x4 sv = *(const f32x4*)(was + j);
            f32x4 dv = *(const f32x4*)(wad + j);
            ps += hv[0]*sv[0] + hv[1]*sv[1] + hv[2]*sv[2] + hv[3]*sv[3];
            pv += hv[0]*dv[0] + hv[1]*dv[1] + hv[2]*dv[2] + hv[3]*dv[3];
        }
        sred[r][seg][0] = ps;
        sred[r][seg][1] = pv;
    }
    __syncthreads();
    if (t < 32) {
        float s = 0.f, d = 0.f;
        #pragma unroll
        for (int j = 0; j < 8; ++j) { s += sred[t][j][0]; d += sred[t][j][1]; }
        s_src[b * Nn + i0 + t] = s;
        s_dst[b * Nn + i0 + t] = d;
        red32[t] = d;
    }
    __syncthreads();
    if (t == 0) {
        float m = red32[0];
        #pragma unroll
        for (int j = 1; j < 32; ++j) m = fmaxf(m, red32[j]);
        unsigned int bits = __builtin_bit_cast(unsigned int, m);
        unsigned int key  = (bits & 0x80000000u) ? ~bits : (bits | 0x80000000u);
        atomicMax(md_key + b, key);
    }
    // ---- 0e: MFMA Wh for own 32 rows; wave w: rows (w&1)*16, f-half (w>>1) ----
    {
        const int rg = (w & 1) << 4;
        const int fh = (w >> 1) << 2;        // nt base 0 or 4
        const float* ha = h + ((size_t)(b * Nn + i0 + rg + n16)) * FIN + quad * 8;
        f32x4 acc[4] = {};
        #pragma unroll
        for (int ks = 0; ks < 8; ++ks) {
            f32x4 h0 = *(const f32x4*)(ha + ks * 32);
            f32x4 h1 = *(const f32x4*)(ha + ks * 32 + 4);
            bf16x8 af;
            af[0] = (short)f2bf(h0[0]); af[1] = (short)f2bf(h0[1]);
            af[2] = (short)f2bf(h0[2]); af[3] = (short)f2bf(h0[3]);
            af[4] = (short)f2bf(h1[0]); af[5] = (short)f2bf(h1[1]);
            af[6] = (short)f2bf(h1[2]); af[7] = (short)f2bf(h1[3]);
            #pragma unroll
            for (int i = 0; i < 4; ++i) {
                bf16x8 bfr = *(const bf16x8*)&WT[(fh + i) * 16 + n16][ks * 32 + quad * 8];
                acc[i] = __builtin_amdgcn_mfma_f32_16x16x32_bf16(af, bfr, acc[i], 0, 0, 0);
            }
        }
        // rows i0..i0+32 => single K = i0/32; same swizzle as proven r4-r6 wh
        const int K   = i0 >> 5;
        const int jl  = rg + (quad << 2);
        const int q2  = jl >> 3;
        const int off = jl & 7;
        unsigned short* wpb = WhB + (((size_t)(b * 64 + K)) << 12)
                                  + (((q2 << 4) + n16) << 3) + off;
        #pragma unroll
        for (int i = 0; i < 4; ++i) {
            ushort4 pk;
            pk.x = f2bf(acc[i][0]); pk.y = f2bf(acc[i][1]);
            pk.z = f2bf(acc[i][2]); pk.w = f2bf(acc[i][3]);
            *(ushort4*)(wpb + ((size_t)(fh + i) << 9)) = pk;
        }
    }

    cg::this_grid().sync();

    // ---- phase 1: r6 K-loop verbatim (sdl/accbuf alias WTbuf) ----
    #pragma unroll
    for (int c = 0; c < 2; ++c) {
        int idx = (c << 10) + (t << 2);
        *(f32x4*)&sdl[idx] = *(const f32x4*)&s_dst[b * Nn + idx];
    }
    if (t < 32) l_red[t] = 0.f;
    __syncthreads();

    const unsigned int key = md_key[b];
    const unsigned int mb_ = (key & 0x80000000u) ? (key ^ 0x80000000u) : ~key;
    const float mdb = __builtin_bit_cast(float, mb_);
    float ssL[2], mi[2];
    #pragma unroll
    for (int ig = 0; ig < 2; ++ig) {
        float ss = s_src[b * Nn + i0 + (ig << 4) + n16];
        float tm = ss + mdb;
        mi[ig]  = fmaxf(tm, GAT_ALPHA * tm) * LOG2E;
        ssL[ig] = ss * LOG2E;
    }

    const unsigned short* wb = WhB + ((size_t)b << 18) + ((size_t)lane << 3);
    f32x4 acc[2][8] = {};
    float ls0 = 0.f, ls1 = 0.f;

    for (int s = 0; s < 16; ++s) {
        const int ks = (s << 2) | w;
        const int kw = ks << 5;
        const unsigned short* wp = wb + ((size_t)ks << 12);
        bf16x8 bfr[8];
        #pragma unroll
        for (int nt = 0; nt < 8; ++nt)
            bfr[nt] = *(const bf16x8*)(wp + (nt << 9));
        f32x4 d0 = *(const f32x4*)&sdl[kw + (quad << 3)];
        f32x4 d1 = *(const f32x4*)&sdl[kw + (quad << 3) + 4];
        float dv[8] = {d0[0],d0[1],d0[2],d0[3],d1[0],d1[1],d1[2],d1[3]};
        #pragma unroll
        for (int ig = 0; ig < 2; ++ig) {
            unsigned long long m64 = msk[(ig << 4) + n16][kw >> 6];
            unsigned int mh = (kw & 32) ? (unsigned int)(m64 >> 32) : (unsigned int)m64;
            mh >>= (quad << 3);
            bf16x8 af;
            float lsl = 0.f;
            #pragma unroll
            for (int jj = 0; jj < 8; ++jj) {
                float u  = __builtin_fmaf(dv[jj], LOG2E, ssL[ig]);
                float lr = fmaxf(u, GAT_ALPHA * u);
                float e  = __builtin_amdgcn_exp2f(lr - mi[ig]);
                e = ((mh >> jj) & 1u) ? e : 0.f;
                unsigned short ub = f2bf(e);
                af[jj] = (short)ub;
                lsl += bf2f(ub);
            }
            if (ig == 0) ls0 += lsl; else ls1 += lsl;
            #pragma unroll
            for (int nt = 0; nt < 8; ++nt)
                acc[ig][nt] = __builtin_amdgcn_mfma_f32_16x16x32_bf16(af, bfr[nt], acc[ig][nt], 0, 0, 0);
        }
    }

    atomicAdd(&l_red[n16], ls0);
    atomicAdd(&l_red[16 + n16], ls1);
    if (w < 2) {
        #pragma unroll
        for (int ig = 0; ig < 2; ++ig)
            #pragma unroll
            for (int nt = 0; nt < 8; ++nt)
                #pragma unroll
                for (int rr = 0; rr < 4; ++rr)
                    acb[(w << 5) + (ig << 4) + (quad << 2) + rr][(nt << 4) + n16] = acc[ig][nt][rr];
    }
    __syncthreads();
    if (w >= 2) {
        #pragma unroll
        for (int ig = 0; ig < 2; ++ig)
            #pragma unroll
            for (int nt = 0; nt < 8; ++nt)
                #pragma unroll
                for (int rr = 0; rr < 4; ++rr)
                    acb[((w - 2) << 5) + (ig << 4) + (quad << 2) + rr][(nt << 4) + n16] += acc[ig][nt][rr];
    }
    __syncthreads();
    float* ob = out + ((size_t)(b * Nn + i0)) * FO;
    #pragma unroll
    for (int c = 0; c < 4; ++c) {
        int flat = (c << 10) + (t << 2);
        int m = flat >> 7, f = flat & 127;
        f32x4 v0 = *(const f32x4*)&acb[m][f];
        f32x4 v1 = *(const f32x4*)&acb[32 + m][f];
        float l = l_red[m];
        f32x4 o;
        #pragma unroll
        for (int j = 0; j < 4; ++j) {
            float x = (v0[j] + v1[j]) / l;
            o[j] = x > 0.f ? x : expm1f(x);
        }
        *(f32x4*)&ob[(size_t)m * FO + f] = o;
    }
}

// ===========================================================================
// FALLBACK path (r6 verbatim) — used only if cooperative launch is rejected.
// ===========================================================================
__global__ __launch_bounds__(256) void gat_prep(
        const float* __restrict__ W, const float* __restrict__ a,
        float* __restrict__ wa, unsigned int* __restrict__ md_key)
{
    __shared__ float pr[32][8];
    __shared__ float pd[32][8];
    const int t = threadIdx.x;
    const int kl = t >> 3, seg = t & 7;
    const int k = blockIdx.x * 32 + kl;
    float ps = 0.f, pv = 0.f;
    const float* wr = W + (size_t)k * FO + seg * 16;
    #pragma unroll
    for (int f = 0; f < 16; f += 4) {
        f32x4 wv = *(const f32x4*)(wr + f);
        f32x4 as = *(const f32x4*)(a + seg * 16 + f);
        f32x4 ad = *(const f32x4*)(a + FO + seg * 16 + f);
        ps += wv[0]*as[0] + wv[1]*as[1] + wv[2]*as[2] + wv[3]*as[3];
        pv += wv[0]*ad[0] + wv[1]*ad[1] + wv[2]*ad[2] + wv[3]*ad[3];
    }
    pr[kl][seg] = ps; pd[kl][seg] = pv;
    __syncthreads();
    if (t < 32) {
        float s = 0.f, d = 0.f;
        #pragma unroll
        for (int j = 0; j < 8; ++j) { s += pr[t][j]; d += pd[t][j]; }
        wa[blockIdx.x * 32 + t]       = s;
        wa[256 + blockIdx.x * 32 + t] = d;
    }
    if (blockIdx.x == 0 && t < 8) md_key[t] = 0u;
}

__global__ __launch_bounds__(256) void gat_wh(
        const float* __restrict__ h, const float* __restrict__ W,
        const float* __restrict__ wa, unsigned short* __restrict__ WhB,
        float* __restrict__ s_src, float* __restrict__ s_dst,
        unsigned int* __restrict__ md_key)
{
    __shared__ unsigned short WT[FO][264];
    __shared__ float wal[512];
    __shared__ float sred[64][4][2];
    __shared__ float red64[64];
    const int t  = threadIdx.x;
    const int b  = blockIdx.x & 7;
    const int n0 = (blockIdx.x >> 3) << 6;

    if (t < 128) *(f32x4*)&wal[t * 4] = *(const f32x4*)&wa[t * 4];
    #pragma unroll
    for (int c = 0; c < 32; ++c) {
        int flat = c * 1024 + t * 4;
        int k = flat >> 7, f = flat & 127;
        f32x4 wv = *(const f32x4*)&W[flat];
        WT[f + 0][k] = f2bf(wv[0]);
        WT[f + 1][k] = f2bf(wv[1]);
        WT[f + 2][k] = f2bf(wv[2]);
        WT[f + 3][k] = f2bf(wv[3]);
    }
    __syncthreads();
    {
        const int row = t >> 2, seg = t & 3;
        const float* hp  = h + ((size_t)(b * Nn + n0 + row)) * FIN + seg * 64;
        const float* was = &wal[seg * 64];
        const float* wad = &wal[256 + seg * 64];
        float ps = 0.f, pv = 0.f;
        #pragma unroll
        for (int j = 0; j < 64; j += 4) {
            f32x4 hv = *(const f32x4*)(hp + j);
            f32x4 sv = *(const f32x4*)(was + j);
            f32x4 dv = *(const f32x4*)(wad + j);
            ps += hv[0]*sv[0] + hv[1]*sv[1] + hv[2]*sv[2] + hv[3]*sv[3];
            pv += hv[0]*dv[0] + hv[1]*dv[1] + hv[2]*dv[2] + hv[3]*dv[3];
        }
        sred[row][seg][0] = ps;
        sred[row][seg][1] = pv;
    }
    __syncthreads();
    if (t < 64) {
        float s = sred[t][0][0] + sred[t][1][0] + sred[t][2][0] + sred[t][3][0];
        float d = sred[t][0][1] + sred[t][1][1] + sred[t][2][1] + sred[t][3][1];
        s_src[b * Nn + n0 + t] = s;
        s_dst[b * Nn + n0 + t] = d;
        red64[t] = d;
    }
    __syncthreads();
    if (t < 16) red64[t] = fmaxf(fmaxf(red64[t], red64[t + 16]),
                                 fmaxf(red64[t + 32], red64[t + 48]));
    __syncthreads();
    if (t == 0) {
        float m = red64[0];
        #pragma unroll
        for (int j = 1; j < 16; ++j) m = fmaxf(m, red64[j]);
        unsigned int bits = __builtin_bit_cast(unsigned int, m);
        unsigned int key  = (bits & 0x80000000u) ? ~bits : (bits | 0x80000000u);
        atomicMax(md_key + b, key);
    }
    const int w = t >> 6, lane = t & 63, n16 = lane & 15, quad = lane >> 4;
    const float* ha = h + ((size_t)(b * Nn + n0 + w * 16 + n16)) * FIN + quad * 8;
    f32x4 acc[8] = {};
    #pragma unroll
    for (int ks = 0; ks < 8; ++ks) {
        f32x4 h0 = *(const f32x4*)(ha + ks * 32);
        f32x4 h1 = *(const f32x4*)(ha + ks * 32 + 4);
        bf16x8 af;
        af[0] = (short)f2bf(h0[0]); af[1] = (short)f2bf(h0[1]);
        af[2] = (short)f2bf(h0[2]); af[3] = (short)f2bf(h0[3]);
        af[4] = (short)f2bf(h1[0]); af[5] = (short)f2bf(h1[1]);
        af[6] = (short)f2bf(h1[2]); af[7] = (short)f2bf(h1[3]);
        #pragma unroll
        for (int nt = 0; nt < 8; ++nt) {
            bf16x8 bfr = *(const bf16x8*)&WT[nt * 16 + n16][ks * 32 + quad * 8];
            acc[nt] = __builtin_amdgcn_mfma_f32_16x16x32_bf16(af, bfr, acc[nt], 0, 0, 0);
        }
    }
    {
        const int K   = (n0 >> 5) + (w >> 1);
        const int jl  = ((w & 1) << 4) + (quad << 2);
        const int q2  = jl >> 3;
        const int off = jl & 7;
        unsigned short* wpb = WhB + (((size_t)(b * 64 + K)) << 12)
                                  + (((q2 << 4) + n16) << 3) + off;
        #pragma unroll
        for (int nt = 0; nt < 8; ++nt) {
            ushort4 pk;
            pk.x = f2bf(acc[nt][0]); pk.y = f2bf(acc[nt][1]);
            pk.z = f2bf(acc[nt][2]); pk.w = f2bf(acc[nt][3]);
            *(ushort4*)(wpb + ((size_t)nt << 9)) = pk;
        }
    }
}

__global__ __launch_bounds__(256, 3) void gat_attn(
        const int* __restrict__ adj,
        const unsigned short* __restrict__ WhB,
        const float* __restrict__ s_src, const float* __restrict__ s_dst,
        const unsigned int* __restrict__ md_key, float* __restrict__ out)
{
    __shared__ float sdl[2048];
    __shared__ unsigned long long msk[32][34];
    __shared__ float accbuf[2][32][132];
    __shared__ float l_red[32];

    const int t = threadIdx.x, w = t >> 6, lane = t & 63;
    const int n16 = lane & 15, quad = lane >> 4;
    const int b  = blockIdx.x & 7;
    const int i0 = (blockIdx.x >> 3) << 5;

    {
        const int* ab = adj + ((size_t)(b * Nn + i0)) * Nn;
        unsigned int* mskw = (unsigned int*)&msk[0][0];
        #pragma unroll 2
        for (int s = 0; s < 8; ++s) {
            const int* p = ab + (s << 13) + (t << 5);
            unsigned int m = 0;
            #pragma unroll
            for (int c = 0; c < 8; ++c) {
                i32x4 v = *(const i32x4*)(p + (c << 2));
                m |= (v[0] > 0 ? 1u : 0u) << (c * 4 + 0);
                m |= (v[1] > 0 ? 1u : 0u) << (c * 4 + 1);
                m |= (v[2] > 0 ? 1u : 0u) << (c * 4 + 2);
                m |= (v[3] > 0 ? 1u : 0u) << (c * 4 + 3);
            }
            const int wi = (s << 8) + t;
            mskw[(wi >> 6) * 68 + (wi & 63)] = m;
        }
    }
    #pragma unroll
    for (int c = 0; c < 2; ++c) {
        int idx = (c << 10) + (t << 2);
        *(f32x4*)&sdl[idx] = *(const f32x4*)&s_dst[b * Nn + idx];
    }
    if (t < 32) l_red[t] = 0.f;
    __syncthreads();

    const unsigned int key = md_key[b];
    const unsigned int mb_ = (key & 0x80000000u) ? (key ^ 0x80000000u) : ~key;
    const float mdb = __builtin_bit_cast(float, mb_);
    float ssL[2], mi[2];
    #pragma unroll
    for (int ig = 0; ig < 2; ++ig) {
        float ss = s_src[b * Nn + i0 + (ig << 4) + n16];
        float tm = ss + mdb;
        mi[ig]  = fmaxf(tm, GAT_ALPHA * tm) * LOG2E;
        ssL[ig] = ss * LOG2E;
    }

    const unsigned short* wb = WhB + ((size_t)b << 18) + ((size_t)lane << 3);
    f32x4 acc[2][8] = {};
    float ls0 = 0.f, ls1 = 0.f;

    for (int s = 0; s < 16; ++s) {
        const int ks = (s << 2) | w;
        const int kw = ks << 5;
        const unsigned short* wp = wb + ((size_t)ks << 12);
        bf16x8 bfr[8];
        #pragma unroll
        for (int nt = 0; nt < 8; ++nt)
            bfr[nt] = *(const bf16x8*)(wp + (nt << 9));
        f32x4 d0 = *(const f32x4*)&sdl[kw + (quad << 3)];
        f32x4 d1 = *(const f32x4*)&sdl[kw + (quad << 3) + 4];
        float dv[8] = {d0[0],d0[1],d0[2],d0[3],d1[0],d1[1],d1[2],d1[3]};
        #pragma unroll
        for (int ig = 0; ig < 2; ++ig) {
            unsigned long long m64 = msk[(ig << 4) + n16][kw >> 6];
            unsigned int mh = (kw & 32) ? (unsigned int)(m64 >> 32) : (unsigned int)m64;
            mh >>= (quad << 3);
            bf16x8 af;
            float lsl = 0.f;
            #pragma unroll
            for (int jj = 0; jj < 8; ++jj) {
                float u  = __builtin_fmaf(dv[jj], LOG2E, ssL[ig]);
                float lr = fmaxf(u, GAT_ALPHA * u);
                float e  = __builtin_amdgcn_exp2f(lr - mi[ig]);
                e = ((mh >> jj) & 1u) ? e : 0.f;
                unsigned short ub = f2bf(e);
                af[jj] = (short)ub;
                lsl += bf2f(ub);
            }
            if (ig == 0) ls0 += lsl; else ls1 += lsl;
            #pragma unroll
            for (int nt = 0; nt < 8; ++nt)
                acc[ig][nt] = __builtin_amdgcn_mfma_f32_16x16x32_bf16(af, bfr[nt], acc[ig][nt], 0, 0, 0);
        }
    }

    atomicAdd(&l_red[n16], ls0);
    atomicAdd(&l_red[16 + n16], ls1);
    if (w < 2) {
        #pragma unroll
        for (int ig = 0; ig < 2; ++ig)
            #pragma unroll
            for (int nt = 0; nt < 8; ++nt)
                #pragma unroll
                for (int rr = 0; rr < 4; ++rr)
                    accbuf[w][(ig << 4) + (quad << 2) + rr][(nt << 4) + n16] = acc[ig][nt][rr];
    }
    __syncthreads();
    if (w >= 2) {
        #pragma unroll
        for (int ig = 0; ig < 2; ++ig)
            #pragma unroll
            for (int nt = 0; nt < 8; ++nt)
                #pragma unroll
                for (int rr = 0; rr < 4; ++rr)
                    accbuf[w - 2][(ig << 4) + (quad << 2) + rr][(nt << 4) + n16] += acc[ig][nt][rr];
    }
    __syncthreads();
    float* ob = out + ((size_t)(b * Nn + i0)) * FO;
    #pragma unroll
    for (int c = 0; c < 4; ++c) {
        int flat = (c << 10) + (t << 2);
        int m = flat >> 7, f = flat & 127;
        f32x4 v0 = *(const f32x4*)&accbuf[0][m][f];
        f32x4 v1 = *(const f32x4*)&accbuf[1][m][f];
        float l = l_red[m];
        f32x4 o;
        #pragma unroll
        for (int j = 0; j < 4; ++j) {
            float x = (v0[j] + v1[j]) / l;
            o[j] = x > 0.f ? x : expm1f(x);
        }
        *(f32x4*)&ob[(size_t)m * FO + f] = o;
    }
}

extern "C" void kernel_launch(void* const* d_in, const int* in_sizes, int n_in,
                              void* d_out, int out_size, void* d_ws, size_t ws_size,
                              hipStream_t stream)
{
    const float* h   = (const float*)d_in[0];
    const int*   adj = (const int*)d_in[1];
    const float* W   = (const float*)d_in[2];
    const float* a   = (const float*)d_in[3];
    float* out = (float*)d_out;

    char* ws = (char*)d_ws;
    unsigned short* WhB   = (unsigned short*)ws;                  // [0, 4 MiB)
    float* s_src          = (float*)(ws + 8388608);               // 64 KiB
    float* s_dst          = (float*)(ws + 8454144);               // 64 KiB
    float* wa             = (float*)(ws + 8519680);               // 2 KiB (fallback only)
    unsigned int* md_key  = (unsigned int*)(ws + 8521728);        // 32 B

    // zero md_key (capture-safe stream-ordered memset)
    hipMemsetAsync(md_key, 0, 32, stream);

    void* args[] = { (void*)&h, (void*)&adj, (void*)&W, (void*)&a,
                     (void*)&WhB, (void*)&s_src, (void*)&s_dst,
                     (void*)&md_key, (void*)&out };
    hipError_t err = hipLaunchCooperativeKernel((const void*)gat_fused,
                                                dim3(512), dim3(256),
                                                args, 0, stream);
    if (err != hipSuccess) {
        // deterministic fallback: proven r6 three-kernel path
        hipLaunchKernelGGL(gat_prep, dim3(8),   dim3(256), 0, stream, W, a, wa, md_key);
        hipLaunchKernelGGL(gat_wh,   dim3(256), dim3(256), 0, stream, h, W, wa, WhB, s_src, s_dst, md_key);
        hipLaunchKernelGGL(gat_attn, dim3(512), dim3(256), 0, stream, adj, WhB, s_src, s_dst, md_key, out);
    }
}

// Round 8
// 240.363 us; speedup vs baseline: 1.3639x; 1.3639x over previous
//
#include <hip/hip_runtime.h>
#include <hip/hip_bf16.h>

#define GAT_ALPHA 0.2f
#define LOG2E 1.4426950408889634f

typedef float f32x4 __attribute__((ext_vector_type(4)));
typedef int   i32x4 __attribute__((ext_vector_type(4)));
typedef short bf16x8 __attribute__((ext_vector_type(8)));

static constexpr int Nn  = 2048;
static constexpr int FIN = 256;
static constexpr int FO  = 128;

static __device__ __forceinline__ unsigned short f2bf(float x) {
    __hip_bfloat16 h = __float2bfloat16(x);
    return __builtin_bit_cast(unsigned short, h);
}
static __device__ __forceinline__ float bf2f(unsigned short u) {
    unsigned int v = ((unsigned int)u) << 16;
    return __builtin_bit_cast(float, v);
}

// ---------------------------------------------------------------------------
// Kernel 0 (prep): wa = W@a (both halves); inits md_key[8]=0 (key of -inf).
// ---------------------------------------------------------------------------
__global__ __launch_bounds__(256) void gat_prep(
        const float* __restrict__ W, const float* __restrict__ a,
        float* __restrict__ wa, unsigned int* __restrict__ md_key)
{
    __shared__ float pr[32][8];
    __shared__ float pd[32][8];
    const int t = threadIdx.x;
    const int kl = t >> 3, seg = t & 7;
    const int k = blockIdx.x * 32 + kl;
    float ps = 0.f, pv = 0.f;
    const float* wr = W + (size_t)k * FO + seg * 16;
    #pragma unroll
    for (int f = 0; f < 16; f += 4) {
        f32x4 wv = *(const f32x4*)(wr + f);
        f32x4 as = *(const f32x4*)(a + seg * 16 + f);
        f32x4 ad = *(const f32x4*)(a + FO + seg * 16 + f);
        ps += wv[0]*as[0] + wv[1]*as[1] + wv[2]*as[2] + wv[3]*as[3];
        pv += wv[0]*ad[0] + wv[1]*ad[1] + wv[2]*ad[2] + wv[3]*ad[3];
    }
    pr[kl][seg] = ps; pd[kl][seg] = pv;
    __syncthreads();
    if (t < 32) {
        float s = 0.f, d = 0.f;
        #pragma unroll
        for (int j = 0; j < 8; ++j) { s += pr[t][j]; d += pd[t][j]; }
        wa[blockIdx.x * 32 + t]       = s;
        wa[256 + blockIdx.x * 32 + t] = d;
    }
    if (blockIdx.x == 0 && t < 8) md_key[t] = 0u;
}

// ---------------------------------------------------------------------------
// Kernel 1 (r6 verbatim): Wh = h@W via MFMA, stored PRE-SWIZZLED in
// B-fragment order WhB[b][K][nt][lane][8]; s_src/s_dst fp32-exact via wa;
// per-batch max(s_dst) via order-preserving uint atomicMax.
// ---------------------------------------------------------------------------
__global__ __launch_bounds__(256) void gat_wh(
        const float* __restrict__ h, const float* __restrict__ W,
        const float* __restrict__ wa, unsigned short* __restrict__ WhB,
        float* __restrict__ s_src, float* __restrict__ s_dst,
        unsigned int* __restrict__ md_key)
{
    __shared__ unsigned short WT[FO][264];
    __shared__ float wal[512];
    __shared__ float sred[64][4][2];
    __shared__ float red64[64];
    const int t  = threadIdx.x;
    const int b  = blockIdx.x & 7;
    const int n0 = (blockIdx.x >> 3) << 6;

    if (t < 128) *(f32x4*)&wal[t * 4] = *(const f32x4*)&wa[t * 4];
    #pragma unroll
    for (int c = 0; c < 32; ++c) {
        int flat = c * 1024 + t * 4;
        int k = flat >> 7, f = flat & 127;
        f32x4 wv = *(const f32x4*)&W[flat];
        WT[f + 0][k] = f2bf(wv[0]);
        WT[f + 1][k] = f2bf(wv[1]);
        WT[f + 2][k] = f2bf(wv[2]);
        WT[f + 3][k] = f2bf(wv[3]);
    }
    __syncthreads();
    {
        const int row = t >> 2, seg = t & 3;
        const float* hp  = h + ((size_t)(b * Nn + n0 + row)) * FIN + seg * 64;
        const float* was = &wal[seg * 64];
        const float* wad = &wal[256 + seg * 64];
        float ps = 0.f, pv = 0.f;
        #pragma unroll
        for (int j = 0; j < 64; j += 4) {
            f32x4 hv = *(const f32x4*)(hp + j);
            f32x4 sv = *(const f32x4*)(was + j);
            f32x4 dv = *(const f32x4*)(wad + j);
            ps += hv[0]*sv[0] + hv[1]*sv[1] + hv[2]*sv[2] + hv[3]*sv[3];
            pv += hv[0]*dv[0] + hv[1]*dv[1] + hv[2]*dv[2] + hv[3]*dv[3];
        }
        sred[row][seg][0] = ps;
        sred[row][seg][1] = pv;
    }
    __syncthreads();
    if (t < 64) {
        float s = sred[t][0][0] + sred[t][1][0] + sred[t][2][0] + sred[t][3][0];
        float d = sred[t][0][1] + sred[t][1][1] + sred[t][2][1] + sred[t][3][1];
        s_src[b * Nn + n0 + t] = s;
        s_dst[b * Nn + n0 + t] = d;
        red64[t] = d;
    }
    __syncthreads();
    if (t < 16) red64[t] = fmaxf(fmaxf(red64[t], red64[t + 16]),
                                 fmaxf(red64[t + 32], red64[t + 48]));
    __syncthreads();
    if (t == 0) {
        float m = red64[0];
        #pragma unroll
        for (int j = 1; j < 16; ++j) m = fmaxf(m, red64[j]);
        unsigned int bits = __builtin_bit_cast(unsigned int, m);
        unsigned int key  = (bits & 0x80000000u) ? ~bits : (bits | 0x80000000u);
        atomicMax(md_key + b, key);
    }
    const int w = t >> 6, lane = t & 63, n16 = lane & 15, quad = lane >> 4;
    const float* ha = h + ((size_t)(b * Nn + n0 + w * 16 + n16)) * FIN + quad * 8;
    f32x4 acc[8] = {};
    #pragma unroll
    for (int ks = 0; ks < 8; ++ks) {
        f32x4 h0 = *(const f32x4*)(ha + ks * 32);
        f32x4 h1 = *(const f32x4*)(ha + ks * 32 + 4);
        bf16x8 af;
        af[0] = (short)f2bf(h0[0]); af[1] = (short)f2bf(h0[1]);
        af[2] = (short)f2bf(h0[2]); af[3] = (short)f2bf(h0[3]);
        af[4] = (short)f2bf(h1[0]); af[5] = (short)f2bf(h1[1]);
        af[6] = (short)f2bf(h1[2]); af[7] = (short)f2bf(h1[3]);
        #pragma unroll
        for (int nt = 0; nt < 8; ++nt) {
            bf16x8 bfr = *(const bf16x8*)&WT[nt * 16 + n16][ks * 32 + quad * 8];
            acc[nt] = __builtin_amdgcn_mfma_f32_16x16x32_bf16(af, bfr, acc[nt], 0, 0, 0);
        }
    }
    {
        const int K   = (n0 >> 5) + (w >> 1);
        const int jl  = ((w & 1) << 4) + (quad << 2);
        const int q2  = jl >> 3;
        const int off = jl & 7;
        unsigned short* wpb = WhB + (((size_t)(b * 64 + K)) << 12)
                                  + (((q2 << 4) + n16) << 3) + off;
        #pragma unroll
        for (int nt = 0; nt < 8; ++nt) {
            ushort4 pk;
            pk.x = f2bf(acc[nt][0]); pk.y = f2bf(acc[nt][1]);
            pk.z = f2bf(acc[nt][2]); pk.w = f2bf(acc[nt][3]);
            *(ushort4*)(wpb + ((size_t)nt << 9)) = pk;
        }
    }
}

// ---------------------------------------------------------------------------
// Kernel 2 (v6): 1024 blocks x 16 i-rows. Occupancy-first latency attack:
//   - LDS 29.5 KB + ~113 regs -> __launch_bounds__(256,4): 16 waves/CU
//     (vs 12 in r6; K-loop scales ~linearly with waves/CU per r7 profile)
//   - in-loop LDS operands (s_dst vals + mask u64) register-prefetched ONE
//     ITERATION AHEAD: removes the ~120-cyc just-in-time ds_read stalls that
//     the r7 profile implicates (VALUBusy 12%, MfmaUtil 2.3%, all pipes idle)
//   - bfr global loads single-buffered: issued at iter top, covered by the
//     ~250-cyc af exp chain (register budget doesn't allow double-buffer)
// Fused adj->bitmask pack prologue (the mandatory HBM stream) as in r6.
// ---------------------------------------------------------------------------
__global__ __launch_bounds__(256, 4) void gat_attn(
        const int* __restrict__ adj,
        const unsigned short* __restrict__ WhB,
        const float* __restrict__ s_src, const float* __restrict__ s_dst,
        const unsigned int* __restrict__ md_key, float* __restrict__ out)
{
    __shared__ float sdl[2048];                       // 8 KB
    __shared__ unsigned long long msk[16][34];        // 4.35 KB
    __shared__ float accbuf[2][16][132];              // 16.9 KB
    __shared__ float l_red[16];

    const int t = threadIdx.x, w = t >> 6, lane = t & 63;
    const int n16 = lane & 15, quad = lane >> 4;
    const int b  = blockIdx.x & 7;                    // batch per XCD
    const int i0 = (blockIdx.x >> 3) << 4;            // 128 i-tiles of 16

    // ---- fused adj -> bitmask prologue (16 rows = 128 KB, coalesced) ----
    {
        const int* ab = adj + ((size_t)(b * Nn + i0)) * Nn;
        unsigned int* mskw = (unsigned int*)&msk[0][0];
        #pragma unroll 2
        for (int s = 0; s < 4; ++s) {
            const int* p = ab + (s << 13) + (t << 5);
            unsigned int m = 0;
            #pragma unroll
            for (int c = 0; c < 8; ++c) {
                i32x4 v = *(const i32x4*)(p + (c << 2));
                m |= (v[0] > 0 ? 1u : 0u) << (c * 4 + 0);
                m |= (v[1] > 0 ? 1u : 0u) << (c * 4 + 1);
                m |= (v[2] > 0 ? 1u : 0u) << (c * 4 + 2);
                m |= (v[3] > 0 ? 1u : 0u) << (c * 4 + 3);
            }
            const int wi = (s << 8) + t;
            mskw[(wi >> 6) * 68 + (wi & 63)] = m;
        }
    }
    #pragma unroll
    for (int c = 0; c < 2; ++c) {
        int idx = (c << 10) + (t << 2);
        *(f32x4*)&sdl[idx] = *(const f32x4*)&s_dst[b * Nn + idx];
    }
    if (t < 16) l_red[t] = 0.f;
    __syncthreads();

    const unsigned int key = md_key[b];
    const unsigned int mb_ = (key & 0x80000000u) ? (key ^ 0x80000000u) : ~key;
    const float mdb = __builtin_bit_cast(float, mb_);
    const float ss  = s_src[b * Nn + i0 + n16];
    const float tm  = ss + mdb;
    const float mi  = fmaxf(tm, GAT_ALPHA * tm) * LOG2E;  // row upper bound (lrelu monotone)
    const float ssL = ss * LOG2E;

    const unsigned short* wb = WhB + ((size_t)b << 18) + ((size_t)lane << 3);
    f32x4 acc[8] = {};
    float ls = 0.f;

    // iteration-0 LDS operand prefetch
    int kw0 = w << 5;
    f32x4 d0 = *(const f32x4*)&sdl[kw0 + (quad << 3)];
    f32x4 d1 = *(const f32x4*)&sdl[kw0 + (quad << 3) + 4];
    unsigned long long m64 = msk[n16][kw0 >> 6];

    for (int s = 0; s < 16; ++s) {
        const int ks = (s << 2) | w;                  // wave k-split, disjoint
        const unsigned short* wp = wb + ((size_t)ks << 12);
        bf16x8 bfr[8];
        #pragma unroll
        for (int nt = 0; nt < 8; ++nt)
            bfr[nt] = *(const bf16x8*)(wp + (nt << 9));    // contiguous 1 KB/wave

        // stage current operands; prefetch NEXT iteration's LDS operands
        f32x4 c0 = d0, c1 = d1;
        unsigned long long cm = m64;
        {
            const int kn = ((s < 15) ? (ks + 4) : w) << 5; // always-valid addr
            d0 = *(const f32x4*)&sdl[kn + (quad << 3)];
            d1 = *(const f32x4*)&sdl[kn + (quad << 3) + 4];
            m64 = msk[n16][kn >> 6];
        }

        const int kwc = ks << 5;
        unsigned int mh = (kwc & 32) ? (unsigned int)(cm >> 32) : (unsigned int)cm;
        mh >>= (quad << 3);
        float dv[8] = {c0[0],c0[1],c0[2],c0[3],c1[0],c1[1],c1[2],c1[3]};
        bf16x8 af;
        float lsl = 0.f;
        #pragma unroll
        for (int jj = 0; jj < 8; ++jj) {
            float u  = __builtin_fmaf(dv[jj], LOG2E, ssL);
            float lr = fmaxf(u, GAT_ALPHA * u);
            float e  = __builtin_amdgcn_exp2f(lr - mi);
            e = ((mh >> jj) & 1u) ? e : 0.f;          // mask == exp(NEG_INF-m)->0
            unsigned short ub = f2bf(e);
            af[jj] = (short)ub;
            lsl += bf2f(ub);                          // denom consistent w/ numerator
        }
        ls += lsl;
        #pragma unroll
        for (int nt = 0; nt < 8; ++nt)
            acc[nt] = __builtin_amdgcn_mfma_f32_16x16x32_bf16(af, bfr[nt], acc[nt], 0, 0, 0);
    }

    atomicAdd(&l_red[n16], ls);
    if (w < 2) {
        #pragma unroll
        for (int nt = 0; nt < 8; ++nt)
            #pragma unroll
            for (int rr = 0; rr < 4; ++rr)
                accbuf[w][(quad << 2) + rr][(nt << 4) + n16] = acc[nt][rr];
    }
    __syncthreads();
    if (w >= 2) {
        #pragma unroll
        for (int nt = 0; nt < 8; ++nt)
            #pragma unroll
            for (int rr = 0; rr < 4; ++rr)
                accbuf[w - 2][(quad << 2) + rr][(nt << 4) + n16] += acc[nt][rr];
    }
    __syncthreads();
    float* ob = out + ((size_t)(b * Nn + i0)) * FO;
    #pragma unroll
    for (int c = 0; c < 2; ++c) {
        int flat = (c << 10) + (t << 2);
        int m = flat >> 7, f = flat & 127;
        f32x4 v0 = *(const f32x4*)&accbuf[0][m][f];
        f32x4 v1 = *(const f32x4*)&accbuf[1][m][f];
        float l = l_red[m];
        f32x4 o;
        #pragma unroll
        for (int j = 0; j < 4; ++j) {
            float x = (v0[j] + v1[j]) / l;
            o[j] = x > 0.f ? x : expm1f(x);
        }
        *(f32x4*)&ob[(size_t)m * FO + f] = o;
    }
}

extern "C" void kernel_launch(void* const* d_in, const int* in_sizes, int n_in,
                              void* d_out, int out_size, void* d_ws, size_t ws_size,
                              hipStream_t stream)
{
    const float* h   = (const float*)d_in[0];
    const int*   adj = (const int*)d_in[1];
    const float* W   = (const float*)d_in[2];
    const float* a   = (const float*)d_in[3];
    float* out = (float*)d_out;

    // ws layout (non-overlapping; s_src/s_dst are 64 KiB EACH):
    char* ws = (char*)d_ws;
    unsigned short* WhB   = (unsigned short*)ws;                  // [0, 4 MiB)
    float* s_src          = (float*)(ws + 8388608);               // 64 KiB
    float* s_dst          = (float*)(ws + 8454144);               // 64 KiB
    float* wa             = (float*)(ws + 8519680);               // 2 KiB
    unsigned int* md_key  = (unsigned int*)(ws + 8521728);        // 32 B

    hipLaunchKernelGGL(gat_prep, dim3(8),    dim3(256), 0, stream, W, a, wa, md_key);
    hipLaunchKernelGGL(gat_wh,   dim3(256),  dim3(256), 0, stream, h, W, wa, WhB, s_src, s_dst, md_key);
    hipLaunchKernelGGL(gat_attn, dim3(1024), dim3(256), 0, stream, adj, WhB, s_src, s_dst, md_key, out);
}